// Round 1
// baseline (1052.934 us; speedup 1.0000x reference)
//
#include <hip/hip_runtime.h>
#include <hip/hip_bf16.h>
#include <math.h>

// Problem constants
#define BB    8
#define HH    160
#define WW    256
#define CC    700
#define KK    250
#define NBINS 750
#define NHIST 30
#define NJIT  60
#define NFRM  90
#define PP    (HH*WW)      // 40960
#define TOUT  500          // NBINS - KK
#define MAGIC (400.0f/750.0f)

// GEMM config
#define BM 64
#define BN 64
#define BKK 32
#define KSPLIT 4
#define KC (PP/KSPLIT)     // 10240

// ws layout (floats)
#define OFF_PART 0
#define SZ_PART  (KSPLIT*480*704)          // 1,351,680
#define OFF_SPAT (OFF_PART + SZ_PART)
#define SZ_SPAT  (BB*NFRM*CC)              // 504,000
#define OFF_LP   (OFF_SPAT + SZ_SPAT)
#define SZ_LP    (BB*CC)                   // 5,600

// ---------------------------------------------------------------------------
// Kernel A: spat_j GEMM. M=480 (b*60+f), N=700 (c), K=40960 (p), split-K=4.
// A generated on the fly from image + eye movements. Partials -> ws.
// ---------------------------------------------------------------------------
__global__ __launch_bounds__(256) void gemm_jit(
    const float* __restrict__ image, const int* __restrict__ eye,
    const float* __restrict__ filt, float* __restrict__ part)
{
    __shared__ float As[BKK][68];   // [k][m], padded: 68 keeps 16B align + bank spread
    __shared__ float Bs[BKK][68];   // [k][n]
    __shared__ int jb[BM], jdy[BM], jdx[BM];

    const int t  = threadIdx.x;
    const int m0 = blockIdx.x * BM;
    const int n0 = blockIdx.y * BN;
    const int kz = blockIdx.z;

    if (t < BM) {
        int m = m0 + t;
        if (m < 480) {
            int b = m / 60, f = m % 60;
            jb[t]  = b;
            jdy[t] = eye[(b*NJIT + f)*2 + 0];
            jdx[t] = eye[(b*NJIT + f)*2 + 1];
        } else {
            jb[t] = -1; jdy[t] = 0; jdx[t] = 0;
        }
    }
    __syncthreads();

    const int mloc = t >> 2;          // 0..63 (row of A / col of B being staged)
    const int k0   = (t & 3) * 8;     // 0,8,16,24
    const int bb   = jb[mloc];
    const int dy   = jdy[mloc];
    const int dx   = jdx[mloc];
    const float* imgb = image + (bb >= 0 ? bb : 0) * PP;

    const int  cg   = n0 + mloc;
    const bool cok  = cg < CC;
    const float* frow = filt + (size_t)(cok ? cg : 0) * PP;

    const int tx = t & 15, ty = t >> 4;

    float acc[4][4] = {};

    const int pend = kz*KC + KC;
    for (int p0 = kz*KC; p0 < pend; p0 += BKK) {
        // ---- stage A (jitter on the fly): As[k][m]
        #pragma unroll
        for (int j = 0; j < 8; ++j) {
            int p = p0 + k0 + j;
            float v = 0.f;
            if (bb >= 0) {
                int r  = (p >> 8) + dy;     // W=256 -> shifts
                int cc = (p & 255) + dx;
                if (r < HH && cc < WW) v = imgb[r*WW + cc];
            }
            As[k0+j][mloc] = v;
        }
        // ---- stage B (filters): Bs[k][n]
        if (cok) {
            float4 b0 = *(const float4*)(frow + p0 + k0);
            float4 b1 = *(const float4*)(frow + p0 + k0 + 4);
            Bs[k0+0][mloc] = b0.x; Bs[k0+1][mloc] = b0.y;
            Bs[k0+2][mloc] = b0.z; Bs[k0+3][mloc] = b0.w;
            Bs[k0+4][mloc] = b1.x; Bs[k0+5][mloc] = b1.y;
            Bs[k0+6][mloc] = b1.z; Bs[k0+7][mloc] = b1.w;
        } else {
            #pragma unroll
            for (int j = 0; j < 8; ++j) Bs[k0+j][mloc] = 0.f;
        }
        __syncthreads();

        #pragma unroll
        for (int k = 0; k < BKK; ++k) {
            float4 a4 = *(const float4*)&As[k][ty*4];   // broadcast across tx
            float4 b4 = *(const float4*)&Bs[k][tx*4];   // conflict-free
            float a[4] = {a4.x, a4.y, a4.z, a4.w};
            float bv[4] = {b4.x, b4.y, b4.z, b4.w};
            #pragma unroll
            for (int i = 0; i < 4; ++i)
                #pragma unroll
                for (int j = 0; j < 4; ++j)
                    acc[i][j] += a[i] * bv[j];
        }
        __syncthreads();
    }

    // write partials (row stride 704 for 16B-aligned float4 stores)
    #pragma unroll
    for (int i = 0; i < 4; ++i) {
        int m = m0 + ty*4 + i;
        if (m >= 480) continue;
        int nb = n0 + tx*4;
        if (nb < CC) {
            float4 v = make_float4(acc[i][0], acc[i][1], acc[i][2], acc[i][3]);
            *(float4*)(part + ((size_t)(kz*480 + m))*704 + nb) = v;
        }
    }
}

// ---------------------------------------------------------------------------
// Kernel B: spat[b][fr][c] = history (fr<30) | sum of 4 K-split partials
// ---------------------------------------------------------------------------
__global__ __launch_bounds__(256) void build_spat(
    const float* __restrict__ hist, const float* __restrict__ part,
    float* __restrict__ spat)
{
    int idx = blockIdx.x*256 + threadIdx.x;
    if (idx >= BB*NFRM*CC) return;
    int c   = idx % CC;
    int rem = idx / CC;
    int fr  = rem % NFRM;
    int b   = rem / NFRM;
    float v;
    if (fr < NHIST) {
        v = hist[(b*NHIST + fr)*CC + c];
    } else {
        int m = b*NJIT + (fr - NHIST);
        v = 0.f;
        #pragma unroll
        for (int ks = 0; ks < KSPLIT; ++ks)
            v += part[((size_t)(ks*480 + m))*704 + c];
    }
    spat[idx] = v;
}

// ---------------------------------------------------------------------------
// Kernel C: per (b,c): gather+upsample 750 vals -> depthwise conv (K=250)
// -> + feedback -> loss -> wave-reduced partial. One wave per block.
// LDS 'ups' uses padded index t + (t>>3): the stride-9 layout makes the
// sliding-window reads (8 consecutive outputs per lane) bank-conflict-free.
// ---------------------------------------------------------------------------
__global__ __launch_bounds__(64) void conv_loss(
    const float* __restrict__ spat, const int* __restrict__ sel,
    const float* __restrict__ wts,  const float* __restrict__ tc,
    const float* __restrict__ fb,   const float* __restrict__ spk,
    const float* __restrict__ tmask, float* __restrict__ lpart)
{
    __shared__ float tcs[256];
    __shared__ float ups[864];   // indices t + (t>>3), t in [0,768)

    const int lane = threadIdx.x;
    const int c = blockIdx.x;
    const int b = blockIdx.y;

    for (int k = lane; k < 256; k += 64)
        tcs[k] = (k < KK) ? tc[c*KK + k] : 0.f;

    const float* spb = spat + (size_t)b*NFRM*CC + c;
    for (int tt = lane; tt < 768; tt += 64) {
        float v = 0.f;
        if (tt < NBINS) {
            int base = (b*NBINS + tt)*2;
            int s0 = sel[base], s1 = sel[base+1];
            float w0 = wts[base], w1 = wts[base+1];
            v = w0 * spb[s0*CC] + w1 * spb[s1*CC];
        }
        ups[tt + (tt >> 3)] = v;
    }
    __syncthreads();

    const int t0 = lane * 8;          // 8 consecutive outputs per lane
    float acc[8] = {};
    float u[8];
    #pragma unroll
    for (int j = 0; j < 8; ++j) { int q = t0+j; u[j] = ups[q + (q>>3)]; }

    #pragma unroll 8
    for (int k = 0; k < 256; ++k) {
        float w = tcs[k];
        #pragma unroll
        for (int j = 0; j < 8; ++j) acc[j] += u[j]*w;
        #pragma unroll
        for (int j = 0; j < 7; ++j) u[j] = u[j+1];
        int q = t0 + k + 8;
        u[7] = ups[q + (q>>3)];
    }

    const size_t bc = (size_t)b*CC + c;
    const float* fbp = fb  + bc*(TOUT+1);
    const float* sp  = spk + bc*NBINS + KK;
    const float* tm  = tmask + (size_t)b*TOUT;
    float lsum = 0.f;
    #pragma unroll
    for (int j = 0; j < 8; ++j) {
        int tt = t0 + j;
        if (tt < TOUT) {
            float g  = acc[j] + fbp[tt];
            float sv = sp[tt];
            lsum += (expf(g) - sv*g) * tm[tt];
        }
    }
    #pragma unroll
    for (int off = 32; off > 0; off >>= 1)
        lsum += __shfl_down(lsum, off);
    if (lane == 0) lpart[bc] = lsum * MAGIC;
}

// ---------------------------------------------------------------------------
// Kernel D: out[b] = sum_c lpart[b][c]  (deterministic tree reduce)
// ---------------------------------------------------------------------------
__global__ __launch_bounds__(256) void reduce_out(
    const float* __restrict__ lpart, float* __restrict__ out)
{
    __shared__ float red[256];
    int b = blockIdx.x, t = threadIdx.x;
    float s = 0.f;
    for (int i = t; i < CC; i += 256) s += lpart[(size_t)b*CC + i];
    red[t] = s; __syncthreads();
    for (int o = 128; o > 0; o >>= 1) {
        if (t < o) red[t] += red[t+o];
        __syncthreads();
    }
    if (t == 0) out[b] = red[0];
}

extern "C" void kernel_launch(void* const* d_in, const int* in_sizes, int n_in,
                              void* d_out, int out_size, void* d_ws, size_t ws_size,
                              hipStream_t stream) {
    const float* image = (const float*)d_in[0];
    const float* spk   = (const float*)d_in[1];
    const int*   eye   = (const int*)d_in[2];
    const float* tmask = (const float*)d_in[3];
    const int*   sel   = (const int*)d_in[4];
    const float* wts   = (const float*)d_in[5];
    const float* filt  = (const float*)d_in[6];
    const float* tc    = (const float*)d_in[7];
    const float* fb    = (const float*)d_in[8];
    const float* hist  = (const float*)d_in[9];
    float* out = (float*)d_out;

    float* ws    = (float*)d_ws;
    float* part  = ws + OFF_PART;
    float* spat  = ws + OFF_SPAT;
    float* lpart = ws + OFF_LP;

    gemm_jit  <<<dim3(8, 11, KSPLIT), 256, 0, stream>>>(image, eye, filt, part);
    build_spat<<<dim3((BB*NFRM*CC + 255)/256), 256, 0, stream>>>(hist, part, spat);
    conv_loss <<<dim3(CC, BB), 64, 0, stream>>>(spat, sel, wts, tc, fb, spk, tmask, lpart);
    reduce_out<<<dim3(BB), 256, 0, stream>>>(lpart, out);
}

// Round 2
// 168.786 us; speedup vs baseline: 6.2383x; 6.2383x over previous
//
#include <hip/hip_runtime.h>
#include <hip/hip_bf16.h>
#include <math.h>

// Problem constants
#define BB    8
#define HH    160
#define WW    256
#define CC    700
#define KK    250
#define NBINS 750
#define NHIST 30
#define NJIT  60
#define NFRM  90
#define PP    (HH*WW)      // 40960
#define TOUT  500
#define MAGIC (400.0f/750.0f)

// Padded GEMM dims
#define MPAD  512          // 480 -> 512 (32 blocks of 16)
#define NPAD  768          // 700 -> 768 (48 blocks of 16)
#define NKT   1280         // K / 32
#define KSPLIT 16
// gemm tiles
#define NSTEP 40           // (40960/16)/64 K-steps per split

typedef __attribute__((ext_vector_type(8))) short short8;
typedef __attribute__((ext_vector_type(4))) float f32x4;

__device__ __forceinline__ unsigned short f2bf(float x) {
    unsigned u = __builtin_bit_cast(unsigned, x);
    u += 0x7fffu + ((u >> 16) & 1u);   // RNE
    return (unsigned short)(u >> 16);
}

__device__ __forceinline__ void gload16(const void* g, void* l) {
    __builtin_amdgcn_global_load_lds(
        (const __attribute__((address_space(1))) unsigned int*)g,
        (__attribute__((address_space(3))) unsigned int*)l, 16, 0, 0);
}

// ---------------------------------------------------------------------------
// pack_a: jittered image -> bf16, fragment-ready layout
// Ap[((mt*1280 + kt)*64 + l)*8 + j] = A[mt*16 + (l&15)][kt*32 + 8*(l>>4) + j]
// ---------------------------------------------------------------------------
__global__ __launch_bounds__(256) void pack_a(
    const float* __restrict__ img, const int* __restrict__ eye,
    unsigned short* __restrict__ Ap)
{
    int tid = blockIdx.x*256 + threadIdx.x;
    int l   = tid & 63;
    int wid = tid >> 6;                 // mt*1280 + kt
    int kt  = wid % NKT;
    int mt  = wid / NKT;                // 0..31
    int m   = mt*16 + (l & 15);
    int kb  = kt*32 + 8*(l >> 4);       // pixel base, multiple of 8

    unsigned short out[8] = {0,0,0,0,0,0,0,0};
    if (m < 480) {
        int b = m / 60, f = m % 60;
        int dy = eye[(b*NJIT + f)*2 + 0];
        int dx = eye[(b*NJIT + f)*2 + 1];
        int r  = (kb >> 8) + dy;
        int c0 = (kb & 255) + dx;
        if (r < HH) {
            const float* row = img + (size_t)b*PP + r*WW;
            #pragma unroll
            for (int j = 0; j < 8; ++j) {
                int c = c0 + j;
                if (c < WW) out[j] = f2bf(row[c]);
            }
        }
    }
    *(short8*)(Ap + ((size_t)wid*64 + l)*8) = *(short8*)out;
}

// ---------------------------------------------------------------------------
// pack_b: filters fp32 -> bf16, fragment-ready layout (rows >= 700 zeroed)
// ---------------------------------------------------------------------------
__global__ __launch_bounds__(256) void pack_b(
    const float* __restrict__ filt, unsigned short* __restrict__ Bp)
{
    int tid = blockIdx.x*256 + threadIdx.x;
    int l   = tid & 63;
    int wid = tid >> 6;                 // nt*1280 + kt
    int kt  = wid % NKT;
    int nt  = wid / NKT;                // 0..47
    int n   = nt*16 + (l & 15);
    int kb  = kt*32 + 8*(l >> 4);

    unsigned short out[8] = {0,0,0,0,0,0,0,0};
    if (n < CC) {
        const float* row = filt + (size_t)n*PP + kb;
        float4 v0 = *(const float4*)(row);
        float4 v1 = *(const float4*)(row + 4);
        out[0] = f2bf(v0.x); out[1] = f2bf(v0.y);
        out[2] = f2bf(v0.z); out[3] = f2bf(v0.w);
        out[4] = f2bf(v1.x); out[5] = f2bf(v1.y);
        out[6] = f2bf(v1.z); out[7] = f2bf(v1.w);
    }
    *(short8*)(Bp + ((size_t)wid*64 + l)*8) = *(short8*)out;
}

// ---------------------------------------------------------------------------
// gemm_mfma: C[m][n] += A[m][k] B[k][n], bf16 MFMA 16x16x32.
// BM=BN=128, BK=64, 4 waves each computing a 64x64 sub-tile (4x4 frags).
// grid (4, 6, KSPLIT). Partials (fp32) -> part[ks][512][768].
// ---------------------------------------------------------------------------
__global__ __launch_bounds__(256) void gemm_mfma(
    const unsigned short* __restrict__ Ap, const unsigned short* __restrict__ Bp,
    float* __restrict__ part)
{
    __shared__ unsigned short As[8192];   // [mtb(8)][ktb(2)][lane(64)][8]
    __shared__ unsigned short Bs[8192];

    const int t = threadIdx.x, l = t & 63, w = t >> 6;
    const int mtile = blockIdx.x, ntile = blockIdx.y, ks = blockIdx.z;
    const int wr = w >> 1, wc = w & 1;

    f32x4 acc[4][4] = {};

    int ktg = ks*80;                      // k-tile (32-wide) cursor
    for (int step = 0; step < NSTEP; ++step, ktg += 2) {
        #pragma unroll
        for (int h = 0; h < 2; ++h) {
            int tb = 2*w + h;             // block row/col this wave stages
            const unsigned short* ga =
                Ap + ((size_t)(mtile*8 + tb)*NKT + ktg)*512 + (size_t)l*8;
            gload16(ga,       &As[(tb*2 + 0)*512]);
            gload16(ga + 512, &As[(tb*2 + 1)*512]);
            const unsigned short* gb =
                Bp + ((size_t)(ntile*8 + tb)*NKT + ktg)*512 + (size_t)l*8;
            gload16(gb,       &Bs[(tb*2 + 0)*512]);
            gload16(gb + 512, &Bs[(tb*2 + 1)*512]);
        }
        __syncthreads();

        #pragma unroll
        for (int ktb = 0; ktb < 2; ++ktb) {
            short8 a[4], b[4];
            #pragma unroll
            for (int i = 0; i < 4; ++i)
                a[i] = *(const short8*)&As[(((wr*4 + i)*2 + ktb)*64 + l)*8];
            #pragma unroll
            for (int j = 0; j < 4; ++j)
                b[j] = *(const short8*)&Bs[(((wc*4 + j)*2 + ktb)*64 + l)*8];
            #pragma unroll
            for (int i = 0; i < 4; ++i)
                #pragma unroll
                for (int j = 0; j < 4; ++j)
                    acc[i][j] = __builtin_amdgcn_mfma_f32_16x16x32_bf16(
                        a[i], b[j], acc[i][j], 0, 0, 0);
        }
        __syncthreads();
    }

    // epilogue: C/D layout col = l&15, row = (l>>4)*4 + reg
    const int rbase = (l >> 4)*4, cl = l & 15;
    #pragma unroll
    for (int i = 0; i < 4; ++i) {
        #pragma unroll
        for (int j = 0; j < 4; ++j) {
            int m = mtile*128 + wr*64 + i*16 + rbase;
            int n = ntile*128 + wc*64 + j*16 + cl;
            float* p = part + ((size_t)ks*MPAD + m)*NPAD + n;
            #pragma unroll
            for (int r = 0; r < 4; ++r) p[(size_t)r*NPAD] = acc[i][j][r];
        }
    }
}

// ---------------------------------------------------------------------------
// build_spat: spat[b][fr][c] = history (fr<30) | sum of KSPLIT partials
// ---------------------------------------------------------------------------
__global__ __launch_bounds__(256) void build_spat(
    const float* __restrict__ hist, const float* __restrict__ part,
    float* __restrict__ spat)
{
    int idx = blockIdx.x*256 + threadIdx.x;
    if (idx >= BB*NFRM*CC) return;
    int c   = idx % CC;
    int rem = idx / CC;
    int fr  = rem % NFRM;
    int b   = rem / NFRM;
    float v;
    if (fr < NHIST) {
        v = hist[(b*NHIST + fr)*CC + c];
    } else {
        int m = b*NJIT + (fr - NHIST);
        v = 0.f;
        #pragma unroll
        for (int kp = 0; kp < KSPLIT; ++kp)
            v += part[((size_t)kp*MPAD + m)*NPAD + c];
    }
    spat[idx] = v;
}

// ---------------------------------------------------------------------------
// conv_loss: per (b,c) gather+upsample -> depthwise conv -> loss partial
// ---------------------------------------------------------------------------
__global__ __launch_bounds__(64) void conv_loss(
    const float* __restrict__ spat, const int* __restrict__ sel,
    const float* __restrict__ wts,  const float* __restrict__ tc,
    const float* __restrict__ fb,   const float* __restrict__ spk,
    const float* __restrict__ tmask, float* __restrict__ lpart)
{
    __shared__ float tcs[256];
    __shared__ float ups[864];   // index t + (t>>3): conflict-free sliding window

    const int lane = threadIdx.x;
    const int c = blockIdx.x;
    const int b = blockIdx.y;

    for (int k = lane; k < 256; k += 64)
        tcs[k] = (k < KK) ? tc[c*KK + k] : 0.f;

    const float* spb = spat + (size_t)b*NFRM*CC + c;
    for (int tt = lane; tt < 768; tt += 64) {
        float v = 0.f;
        if (tt < NBINS) {
            int base = (b*NBINS + tt)*2;
            int s0 = sel[base], s1 = sel[base+1];
            float w0 = wts[base], w1 = wts[base+1];
            v = w0 * spb[s0*CC] + w1 * spb[s1*CC];
        }
        ups[tt + (tt >> 3)] = v;
    }
    __syncthreads();

    const int t0 = lane * 8;
    float acc[8] = {};
    float u[8];
    #pragma unroll
    for (int j = 0; j < 8; ++j) { int q = t0+j; u[j] = ups[q + (q>>3)]; }

    #pragma unroll 8
    for (int k = 0; k < 256; ++k) {
        float w = tcs[k];
        #pragma unroll
        for (int j = 0; j < 8; ++j) acc[j] += u[j]*w;
        #pragma unroll
        for (int j = 0; j < 7; ++j) u[j] = u[j+1];
        int q = t0 + k + 8;
        u[7] = ups[q + (q>>3)];
    }

    const size_t bc = (size_t)b*CC + c;
    const float* fbp = fb  + bc*(TOUT+1);
    const float* sp  = spk + bc*NBINS + KK;
    const float* tm  = tmask + (size_t)b*TOUT;
    float lsum = 0.f;
    #pragma unroll
    for (int j = 0; j < 8; ++j) {
        int tt = t0 + j;
        if (tt < TOUT) {
            float g  = acc[j] + fbp[tt];
            float sv = sp[tt];
            lsum += (expf(g) - sv*g) * tm[tt];
        }
    }
    #pragma unroll
    for (int off = 32; off > 0; off >>= 1)
        lsum += __shfl_down(lsum, off);
    if (lane == 0) lpart[bc] = lsum * MAGIC;
}

__global__ __launch_bounds__(256) void reduce_out(
    const float* __restrict__ lpart, float* __restrict__ out)
{
    __shared__ float red[256];
    int b = blockIdx.x, t = threadIdx.x;
    float s = 0.f;
    for (int i = t; i < CC; i += 256) s += lpart[(size_t)b*CC + i];
    red[t] = s; __syncthreads();
    for (int o = 128; o > 0; o >>= 1) {
        if (t < o) red[t] += red[t+o];
        __syncthreads();
    }
    if (t == 0) out[b] = red[0];
}

extern "C" void kernel_launch(void* const* d_in, const int* in_sizes, int n_in,
                              void* d_out, int out_size, void* d_ws, size_t ws_size,
                              hipStream_t stream) {
    const float* image = (const float*)d_in[0];
    const float* spk   = (const float*)d_in[1];
    const int*   eye   = (const int*)d_in[2];
    const float* tmask = (const float*)d_in[3];
    const int*   sel   = (const int*)d_in[4];
    const float* wts   = (const float*)d_in[5];
    const float* filt  = (const float*)d_in[6];
    const float* tc    = (const float*)d_in[7];
    const float* fb    = (const float*)d_in[8];
    const float* hist  = (const float*)d_in[9];
    float* out = (float*)d_out;

    unsigned short* Ap = (unsigned short*)d_ws;                 // 512*40960 bf16
    unsigned short* Bp = Ap + (size_t)MPAD*PP;                  // 768*40960 bf16
    float* part  = (float*)(Bp + (size_t)NPAD*PP);              // 16*512*768 f32
    float* spat  = part + (size_t)KSPLIT*MPAD*NPAD;             // 8*90*700 f32
    float* lpart = spat + (size_t)BB*NFRM*CC;                   // 8*700 f32

    pack_a<<<dim3(32*NKT*64/256), 256, 0, stream>>>(image, eye, Ap);
    pack_b<<<dim3(48*NKT*64/256), 256, 0, stream>>>(filt, Bp);
    gemm_mfma<<<dim3(4, 6, KSPLIT), 256, 0, stream>>>(Ap, Bp, part);
    build_spat<<<dim3((BB*NFRM*CC + 255)/256), 256, 0, stream>>>(hist, part, spat);
    conv_loss<<<dim3(CC, BB), 64, 0, stream>>>(spat, sel, wts, tc, fb, spk, tmask, lpart);
    reduce_out<<<dim3(BB), 256, 0, stream>>>(lpart, out);
}

// Round 3
// 156.687 us; speedup vs baseline: 6.7200x; 1.0772x over previous
//
#include <hip/hip_runtime.h>
#include <hip/hip_bf16.h>
#include <math.h>

// Problem constants
#define BB    8
#define HH    160
#define WW    256
#define CC    700
#define KK    250
#define NBINS 750
#define NHIST 30
#define NJIT  60
#define NFRM  90
#define PP    (HH*WW)      // 40960
#define TOUT  500
#define MAGIC (400.0f/750.0f)

// Padded GEMM dims
#define MPAD  512          // 480 -> 512 (32 tiles of 16)
#define NPAD  768          // 700 -> 768 (48 tiles of 16)
#define NKT   1280         // K / 32
#define KSPLIT 20
#define NSTEP 32           // (1280/20) ktiles / 2 per BK=64 step
#define PACKA_BLKS (32*NKT/4)   // 10240
#define PACKB_BLKS (48*NKT/4)   // 15360

typedef __attribute__((ext_vector_type(8))) short short8;
typedef __attribute__((ext_vector_type(4))) float f32x4;

__device__ __forceinline__ unsigned short f2bf(float x) {
    unsigned u = __builtin_bit_cast(unsigned, x);
    u += 0x7fffu + ((u >> 16) & 1u);   // RNE
    return (unsigned short)(u >> 16);
}

__device__ __forceinline__ void gload16(const void* g, void* l) {
    __builtin_amdgcn_global_load_lds(
        (const __attribute__((address_space(1))) unsigned int*)g,
        (__attribute__((address_space(3))) unsigned int*)l, 16, 0, 0);
}

// ---------------------------------------------------------------------------
// pack_ab: fragment-ready bf16 packing for both operands (one launch).
//  A: jittered image on the fly.  B: filters fp32->bf16 (rows >= 700 zero).
// Layout: X[((tile16*1280 + kt)*64 + l)*8 + j] = X[tile*16 + (l&15)][kt*32 + 8*(l>>4) + j]
// ---------------------------------------------------------------------------
__global__ __launch_bounds__(256) void pack_ab(
    const float* __restrict__ img, const int* __restrict__ eye,
    const float* __restrict__ filt,
    unsigned short* __restrict__ Ap, unsigned short* __restrict__ Bp)
{
    int bid = blockIdx.x;
    if (bid < PACKA_BLKS) {
        int tid = bid*256 + threadIdx.x;
        int l   = tid & 63;
        int wid = tid >> 6;                 // mt*1280 + kt
        int kt  = wid % NKT;
        int mt  = wid / NKT;                // 0..31
        int m   = mt*16 + (l & 15);
        int kb  = kt*32 + 8*(l >> 4);

        unsigned short out[8] = {0,0,0,0,0,0,0,0};
        if (m < 480) {
            int b = m / 60, f = m % 60;
            int dy = eye[(b*NJIT + f)*2 + 0];
            int dx = eye[(b*NJIT + f)*2 + 1];
            int r  = (kb >> 8) + dy;
            int c0 = (kb & 255) + dx;
            if (r < HH) {
                const float* row = img + (size_t)b*PP + r*WW;
                #pragma unroll
                for (int j = 0; j < 8; ++j) {
                    int c = c0 + j;
                    if (c < WW) out[j] = f2bf(row[c]);
                }
            }
        }
        *(short8*)(Ap + ((size_t)wid*64 + l)*8) = *(short8*)out;
    } else {
        int tid = (bid - PACKA_BLKS)*256 + threadIdx.x;
        int l   = tid & 63;
        int wid = tid >> 6;                 // nt*1280 + kt
        int kt  = wid % NKT;
        int nt  = wid / NKT;                // 0..47
        int n   = nt*16 + (l & 15);
        int kb  = kt*32 + 8*(l >> 4);

        unsigned short out[8] = {0,0,0,0,0,0,0,0};
        if (n < CC) {
            const float* row = filt + (size_t)n*PP + kb;
            float4 v0 = *(const float4*)(row);
            float4 v1 = *(const float4*)(row + 4);
            out[0] = f2bf(v0.x); out[1] = f2bf(v0.y);
            out[2] = f2bf(v0.z); out[3] = f2bf(v0.w);
            out[4] = f2bf(v1.x); out[5] = f2bf(v1.y);
            out[6] = f2bf(v1.z); out[7] = f2bf(v1.w);
        }
        *(short8*)(Bp + ((size_t)wid*64 + l)*8) = *(short8*)out;
    }
}

// ---------------------------------------------------------------------------
// gemm_mfma: bf16 MFMA 16x16x32. BM=BN=128, BK=64, 4 waves (2x2), each a
// 64x64 sub-tile (4x4 frags). grid (4, 6, KSPLIT) = 480 blocks.
// ---------------------------------------------------------------------------
__global__ __launch_bounds__(256) void gemm_mfma(
    const unsigned short* __restrict__ Ap, const unsigned short* __restrict__ Bp,
    float* __restrict__ part)
{
    __shared__ unsigned short As[8192];   // [mtb(8)][ktb(2)][lane(64)][8]
    __shared__ unsigned short Bs[8192];

    const int t = threadIdx.x, l = t & 63, w = t >> 6;
    const int mtile = blockIdx.x, ntile = blockIdx.y, ks = blockIdx.z;
    const int wr = w >> 1, wc = w & 1;

    f32x4 acc[4][4] = {};

    int ktg = ks*(NKT/KSPLIT);            // 64 ktiles per split
    for (int step = 0; step < NSTEP; ++step, ktg += 2) {
        #pragma unroll
        for (int h = 0; h < 2; ++h) {
            int tb = 2*w + h;
            const unsigned short* ga =
                Ap + ((size_t)(mtile*8 + tb)*NKT + ktg)*512 + (size_t)l*8;
            gload16(ga,       &As[(tb*2 + 0)*512]);
            gload16(ga + 512, &As[(tb*2 + 1)*512]);
            const unsigned short* gb =
                Bp + ((size_t)(ntile*8 + tb)*NKT + ktg)*512 + (size_t)l*8;
            gload16(gb,       &Bs[(tb*2 + 0)*512]);
            gload16(gb + 512, &Bs[(tb*2 + 1)*512]);
        }
        __syncthreads();

        #pragma unroll
        for (int ktb = 0; ktb < 2; ++ktb) {
            short8 a[4], b[4];
            #pragma unroll
            for (int i = 0; i < 4; ++i)
                a[i] = *(const short8*)&As[(((wr*4 + i)*2 + ktb)*64 + l)*8];
            #pragma unroll
            for (int j = 0; j < 4; ++j)
                b[j] = *(const short8*)&Bs[(((wc*4 + j)*2 + ktb)*64 + l)*8];
            #pragma unroll
            for (int i = 0; i < 4; ++i)
                #pragma unroll
                for (int j = 0; j < 4; ++j)
                    acc[i][j] = __builtin_amdgcn_mfma_f32_16x16x32_bf16(
                        a[i], b[j], acc[i][j], 0, 0, 0);
        }
        __syncthreads();
    }

    // epilogue: C/D layout col = l&15, row = (l>>4)*4 + reg
    const int rbase = (l >> 4)*4, cl = l & 15;
    #pragma unroll
    for (int i = 0; i < 4; ++i) {
        #pragma unroll
        for (int j = 0; j < 4; ++j) {
            int m = mtile*128 + wr*64 + i*16 + rbase;
            int n = ntile*128 + wc*64 + j*16 + cl;
            float* p = part + ((size_t)ks*MPAD + m)*NPAD + n;
            #pragma unroll
            for (int r = 0; r < 4; ++r) p[(size_t)r*NPAD] = acc[i][j][r];
        }
    }
}

// ---------------------------------------------------------------------------
// build_spat: spat[b][fr][c] = history (fr<30) | sum of KSPLIT partials
// ---------------------------------------------------------------------------
__global__ __launch_bounds__(256) void build_spat(
    const float* __restrict__ hist, const float* __restrict__ part,
    float* __restrict__ spat)
{
    int idx = blockIdx.x*256 + threadIdx.x;
    if (idx >= BB*NFRM*CC) return;
    int c   = idx % CC;
    int rem = idx / CC;
    int fr  = rem % NFRM;
    int b   = rem / NFRM;
    float v;
    if (fr < NHIST) {
        v = hist[(b*NHIST + fr)*CC + c];
    } else {
        int m = b*NJIT + (fr - NHIST);
        v = 0.f;
        #pragma unroll
        for (int kp = 0; kp < KSPLIT; ++kp)
            v += part[((size_t)kp*MPAD + m)*NPAD + c];
    }
    spat[idx] = v;
}

// ---------------------------------------------------------------------------
// conv_loss: per (b,c) gather+upsample -> depthwise conv (chunked-8 rolling
// window, all-static register indexing) -> loss partial. One wave per block.
// ---------------------------------------------------------------------------
__global__ __launch_bounds__(64) void conv_loss(
    const float* __restrict__ spat, const int* __restrict__ sel,
    const float* __restrict__ wts,  const float* __restrict__ tc,
    const float* __restrict__ fb,   const float* __restrict__ spk,
    const float* __restrict__ tmask, float* __restrict__ lpart)
{
    __shared__ float tcs[256];
    __shared__ float ups[864];   // index t + (t>>3): conflict-free sliding window

    const int lane = threadIdx.x;
    const int c = blockIdx.x;
    const int b = blockIdx.y;

    for (int k = lane; k < 256; k += 64)
        tcs[k] = (k < KK) ? tc[c*KK + k] : 0.f;

    const float* spb = spat + (size_t)b*NFRM*CC + c;
    for (int tt = lane; tt < 768; tt += 64) {
        float v = 0.f;
        if (tt < NBINS) {
            int base = (b*NBINS + tt)*2;
            int s0 = sel[base], s1 = sel[base+1];
            float w0 = wts[base], w1 = wts[base+1];
            v = w0 * spb[s0*CC] + w1 * spb[s1*CC];
        }
        ups[tt + (tt >> 3)] = v;
    }
    __syncthreads();

    const int t0 = lane * 8;          // 8 consecutive outputs per lane
    float u[16];
    #pragma unroll
    for (int j = 0; j < 16; ++j) { int q = t0 + j; u[j] = ups[q + (q >> 3)]; }

    float acc[8] = {};
    #pragma unroll 4
    for (int kc = 0; kc < 248; kc += 8) {
        #pragma unroll
        for (int kk = 0; kk < 8; ++kk) {
            float w = tcs[kc + kk];
            #pragma unroll
            for (int j = 0; j < 8; ++j) acc[j] += w * u[kk + j];
        }
        #pragma unroll
        for (int j = 0; j < 8; ++j) u[j] = u[j + 8];
        #pragma unroll
        for (int j = 0; j < 8; ++j) {
            int q = t0 + kc + 16 + j;
            u[j + 8] = ups[q + (q >> 3)];
        }
    }
    #pragma unroll
    for (int kk = 0; kk < 8; ++kk) {     // last chunk (taps 248..255, zero-padded)
        float w = tcs[248 + kk];
        #pragma unroll
        for (int j = 0; j < 8; ++j) acc[j] += w * u[kk + j];
    }

    const size_t bc = (size_t)b*CC + c;
    const float* fbp = fb  + bc*(TOUT+1);
    const float* sp  = spk + bc*NBINS + KK;
    const float* tm  = tmask + (size_t)b*TOUT;
    float lsum = 0.f;
    #pragma unroll
    for (int j = 0; j < 8; ++j) {
        int tt = t0 + j;
        if (tt < TOUT) {
            float g  = acc[j] + fbp[tt];
            float sv = sp[tt];
            lsum += (__expf(g) - sv*g) * tm[tt];
        }
    }
    #pragma unroll
    for (int off = 32; off > 0; off >>= 1)
        lsum += __shfl_down(lsum, off);
    if (lane == 0) lpart[bc] = lsum * MAGIC;
}

__global__ __launch_bounds__(256) void reduce_out(
    const float* __restrict__ lpart, float* __restrict__ out)
{
    __shared__ float red[256];
    int b = blockIdx.x, t = threadIdx.x;
    float s = 0.f;
    for (int i = t; i < CC; i += 256) s += lpart[(size_t)b*CC + i];
    red[t] = s; __syncthreads();
    for (int o = 128; o > 0; o >>= 1) {
        if (t < o) red[t] += red[t+o];
        __syncthreads();
    }
    if (t == 0) out[b] = red[0];
}

extern "C" void kernel_launch(void* const* d_in, const int* in_sizes, int n_in,
                              void* d_out, int out_size, void* d_ws, size_t ws_size,
                              hipStream_t stream) {
    const float* image = (const float*)d_in[0];
    const float* spk   = (const float*)d_in[1];
    const int*   eye   = (const int*)d_in[2];
    const float* tmask = (const float*)d_in[3];
    const int*   sel   = (const int*)d_in[4];
    const float* wts   = (const float*)d_in[5];
    const float* filt  = (const float*)d_in[6];
    const float* tc    = (const float*)d_in[7];
    const float* fb    = (const float*)d_in[8];
    const float* hist  = (const float*)d_in[9];
    float* out = (float*)d_out;

    unsigned short* Ap = (unsigned short*)d_ws;                 // 512*40960 bf16
    unsigned short* Bp = Ap + (size_t)MPAD*PP;                  // 768*40960 bf16
    float* part  = (float*)(Bp + (size_t)NPAD*PP);              // 20*512*768 f32
    float* spat  = part + (size_t)KSPLIT*MPAD*NPAD;             // 8*90*700 f32
    float* lpart = spat + (size_t)BB*NFRM*CC;                   // 8*700 f32

    pack_ab  <<<dim3(PACKA_BLKS + PACKB_BLKS), 256, 0, stream>>>(image, eye, filt, Ap, Bp);
    gemm_mfma<<<dim3(4, 6, KSPLIT), 256, 0, stream>>>(Ap, Bp, part);
    build_spat<<<dim3((BB*NFRM*CC + 255)/256), 256, 0, stream>>>(hist, part, spat);
    conv_loss<<<dim3(CC, BB), 64, 0, stream>>>(spat, sel, wts, tc, fb, spk, tmask, lpart);
    reduce_out<<<dim3(BB), 256, 0, stream>>>(lpart, out);
}